// Round 16
// baseline (4329.469 us; speedup 1.0000x reference)
//
#include <hip/hip_runtime.h>
#include <hip/hip_bf16.h>

typedef unsigned long long ull;
typedef unsigned int uint;

#define NB 32
#define NFEAT 196
#define SEQL 64
#define ED 1024
#define HD 1024
#define VOC 32000
#define NCOMB 260                  // NFEAT + SEQL
#define NROWS (NB*NCOMB)           // 8320
#define NTILE 2000                 // 16-row vocab tiles
#define LBLK (NTILE/4)             // 500 logits blocks
#define RESC_MARGIN 4.0e-3f        // > 2x max 2-term error (~1.3e-3)
#define MAXCAND 32

typedef __attribute__((ext_vector_type(8))) short s16x8;   // 8 bf16 = 4 VGPRs
typedef __attribute__((ext_vector_type(4))) float f32x4;
typedef __attribute__((ext_vector_type(4))) uint  u32x4;

union FragU { u32x4 u; s16x8 s; };

#define DOT4(acc, wv, xv) acc = fmaf((wv).x,(xv).x, fmaf((wv).y,(xv).y, fmaf((wv).z,(xv).z, fmaf((wv).w,(xv).w,(acc)))))

__device__ __forceinline__ uint enc_f32(float f) {
    uint u = __float_as_uint(f);
    return (u & 0x80000000u) ? ~u : (u | 0x80000000u);
}

// full split (hi + residual lo). Used for attention (3-term path).
__device__ __forceinline__ void split2(float a, float b, uint& hi, uint& lo) {
    __hip_bfloat162 h2 = __float22bfloat162_rn(make_float2(a, b));
    float2 hf = __bfloat1622float2(h2);
    __hip_bfloat162 l2 = __float22bfloat162_rn(make_float2(a - hf.x, b - hf.y));
    hi = *(uint*)&h2;
    lo = *(uint*)&l2;
}
__device__ __forceinline__ uint cvt2(float a, float b) {
    __hip_bfloat162 h2 = __float22bfloat162_rn(make_float2(a, b));
    return *(uint*)&h2;
}

// nontemporal float4 store
__device__ __forceinline__ void nt_store4(float* p, float a, float b, float c, float d) {
    f32x4 v = {a, b, c, d};
    __builtin_nontemporal_store(v, (f32x4*)p);
}

// ---------------------------------------------------------------------------
// gh body: gh[g][j][b] = (W_hh rows {j, H+j, 2H+j}) . h[b]
// ---------------------------------------------------------------------------
__device__ __forceinline__ void gh_body(
    int j, const float* __restrict__ W_hh, const float* __restrict__ h,
    float* __restrict__ gh, int w, int l)
{
    const int b0 = w*8;
    float a[3][8];
#pragma unroll
    for (int g = 0; g < 3; ++g)
#pragma unroll
        for (int i = 0; i < 8; ++i) a[g][i] = 0.f;

    const float* Ur = W_hh + (size_t)j*HD;
    const float* Uz = W_hh + (size_t)(HD + j)*HD;
    const float* Un = W_hh + (size_t)(2*HD + j)*HD;
#pragma unroll
    for (int q = 0; q < 4; ++q) {
        const int k = q*256 + l*4;
        const float4 ur = *(const float4*)(Ur + k);
        const float4 uz = *(const float4*)(Uz + k);
        const float4 un = *(const float4*)(Un + k);
#pragma unroll
        for (int i = 0; i < 8; ++i) {
            const float4 hv = *(const float4*)(h + (size_t)(b0+i)*HD + k);
            DOT4(a[0][i], ur, hv);
            DOT4(a[1][i], uz, hv);
            DOT4(a[2][i], un, hv);
        }
    }
    int s = (l >> 5) & 1;
    int ib = s*4;
    float tA[3][4];
#pragma unroll
    for (int g = 0; g < 3; ++g)
#pragma unroll
        for (int ii = 0; ii < 4; ++ii) {
            const float send = a[g][(1^s)*4 + ii];
            tA[g][ii] = a[g][s*4 + ii] + __shfl_xor(send, 32);
        }
    s = (l >> 4) & 1; ib += s*2;
    float tB[3][2];
#pragma unroll
    for (int g = 0; g < 3; ++g)
#pragma unroll
        for (int jj = 0; jj < 2; ++jj) {
            const float send = tA[g][(1^s)*2 + jj];
            tB[g][jj] = tA[g][s*2 + jj] + __shfl_xor(send, 16);
        }
    s = (l >> 3) & 1; ib += s;
    float fg[3];
#pragma unroll
    for (int g = 0; g < 3; ++g) {
        const float send = tB[g][1^s];
        fg[g] = tB[g][s] + __shfl_xor(send, 8);
    }
#pragma unroll
    for (int mm = 4; mm >= 1; mm >>= 1)
#pragma unroll
        for (int g = 0; g < 3; ++g) fg[g] += __shfl_xor(fg[g], mm);

    if ((l & 7) == 0) {
        const int b = b0 + ib;
        gh[(size_t)(0*HD + j)*NB + b] = fg[0];
        gh[(size_t)(1*HD + j)*NB + b] = fg[1];
        gh[(size_t)(2*HD + j)*NB + b] = fg[2];
    }
}

// ---------------------------------------------------------------------------
// 1) Build combined; zero outputs[:,0,:] (nt).
// ---------------------------------------------------------------------------
__global__ void __launch_bounds__(256) k_build(
    const float* __restrict__ features, const int* __restrict__ captions,
    const float* __restrict__ emb, float* __restrict__ combined,
    float* __restrict__ out)
{
    const int bid = blockIdx.x;
    const int t = threadIdx.x;
    if (bid < NROWS) {
        const int b = bid / NCOMB;
        const int i = bid - b*NCOMB;
        const float* src = (i < NFEAT)
            ? (features + ((size_t)(b*NFEAT + i))*ED)
            : (emb + (size_t)captions[b*SEQL + (i - NFEAT)]*ED);
        float4* dst4 = (float4*)(combined + (size_t)bid*ED);
        const float4* s4 = (const float4*)src;
        dst4[t] = s4[t];
    } else {
        const int z = bid - NROWS;           // 0..999
        const int m = z*1024 + t*4;
        if (m < NB*VOC) {
            const int b = m / VOC;
            const int v = m - b*VOC;
            nt_store4(out + (size_t)b*((size_t)SEQL*VOC) + v, 0.f, 0.f, 0.f, 0.f);
        }
    }
}

// ---------------------------------------------------------------------------
// 1b) Pack Wa1 into hi/lo bf16 B-fragments (attn stays 3-term).
// ---------------------------------------------------------------------------
__global__ void __launch_bounds__(256) k_pack_w1(
    const float* __restrict__ Wa1, uint* __restrict__ W1hi, uint* __restrict__ W1lo)
{
    const int eid = blockIdx.x*256 + threadIdx.x;      // 0..131071
    const int lane = eid & 63;
    const int ks = (eid >> 6) & 31;
    const int ct = eid >> 11;                          // 0..63
    const int c = ct*16 + (lane & 15);
    const int k0 = ks*32 + ((lane >> 4) & 3)*4;
    const float4 wa = *(const float4*)&Wa1[(size_t)c*ED + k0];
    const float4 wb = *(const float4*)&Wa1[(size_t)c*ED + k0 + 16];
    uint hi[4], lo[4];
    split2(wa.x, wa.y, hi[0], lo[0]);
    split2(wa.z, wa.w, hi[1], lo[1]);
    split2(wb.x, wb.y, hi[2], lo[2]);
    split2(wb.z, wb.w, hi[3], lo[3]);
    *(u32x4*)&W1hi[(size_t)eid*4] = (u32x4){hi[0], hi[1], hi[2], hi[3]};
    *(u32x4*)&W1lo[(size_t)eid*4] = (u32x4){lo[0], lo[1], lo[2], lo[3]};
}

// ---------------------------------------------------------------------------
// 1c) Pack W_fc into hi-only bf16 A-fragments (2-term logits; argmax made
//     exact by k_rescore).
// ---------------------------------------------------------------------------
__global__ void __launch_bounds__(256) k_pack_wfc(
    const float* __restrict__ W_fc, uint* __restrict__ Whi)
{
    const int eid = blockIdx.x*256 + threadIdx.x;
    const int lane = eid & 63;
    const int ks = (eid >> 6) & 31;
    const int tile = eid >> 11;                        // 0..1999
    const int row = tile*16 + (lane & 15);
    const int k0 = ks*32 + ((lane >> 4) & 3)*4;
    const float4 wa = *(const float4*)&W_fc[(size_t)row*HD + k0];
    const float4 wb = *(const float4*)&W_fc[(size_t)row*HD + k0 + 16];
    *(u32x4*)&Whi[(size_t)eid*4] = (u32x4){cvt2(wa.x, wa.y), cvt2(wa.z, wa.w),
                                           cvt2(wb.x, wb.y), cvt2(wb.z, wb.w)};
}

// ---------------------------------------------------------------------------
// 2) Attention GEMM via MFMA hi/lo 3-term (R13/R15 proven config).
// ---------------------------------------------------------------------------
__global__ void __launch_bounds__(256) k_attn_mfma(
    const float* __restrict__ combined, const uint* __restrict__ W1hi,
    const uint* __restrict__ W1lo, const float* __restrict__ ba1,
    const float* __restrict__ Wa2, float* __restrict__ partials)
{
    const int t = threadIdx.x;
    const int w = t >> 6, l = t & 63;
    const int lane16 = l & 15, qk = (l >> 4) & 3;
    const int rt = blockIdx.x*4 + w;
    const int cg0 = blockIdx.y*2;

    const float* Arow = combined + (size_t)(rt*16 + lane16)*ED;
    const u32x4* bh_base = (const u32x4*)W1hi + l;
    const u32x4* bl_base = (const u32x4*)W1lo + l;

    f32x4 acc[2][4];
#pragma unroll
    for (int c = 0; c < 2; ++c)
#pragma unroll
        for (int i = 0; i < 4; ++i) acc[c][i] = (f32x4){0.f,0.f,0.f,0.f};

#pragma unroll 2
    for (int ks = 0; ks < 32; ++ks) {
        const int k0 = ks*32 + qk*4;
        const float4 aa = *(const float4*)(Arow + k0);
        const float4 ab = *(const float4*)(Arow + k0 + 16);
        FragU ahi, alo;
        uint h0,l0_,h1,l1_,h2,l2_,h3,l3_;
        split2(aa.x, aa.y, h0, l0_);
        split2(aa.z, aa.w, h1, l1_);
        split2(ab.x, ab.y, h2, l2_);
        split2(ab.z, ab.w, h3, l3_);
        ahi.u = (u32x4){h0, h1, h2, h3};
        alo.u = (u32x4){l0_, l1_, l2_, l3_};
#pragma unroll
        for (int c = 0; c < 2; ++c) {
#pragma unroll
            for (int i = 0; i < 4; ++i) {
                const size_t idx = (((size_t)((cg0 + c)*4 + i))*32 + ks)*64;
                FragU bh_, bl_;
                bh_.u = bh_base[idx];
                bl_.u = bl_base[idx];
                acc[c][i] = __builtin_amdgcn_mfma_f32_16x16x32_bf16(ahi.s, bh_.s, acc[c][i], 0, 0, 0);
                acc[c][i] = __builtin_amdgcn_mfma_f32_16x16x32_bf16(ahi.s, bl_.s, acc[c][i], 0, 0, 0);
                acc[c][i] = __builtin_amdgcn_mfma_f32_16x16x32_bf16(alo.s, bh_.s, acc[c][i], 0, 0, 0);
            }
        }
    }

#pragma unroll
    for (int c = 0; c < 2; ++c) {
        const int cg = cg0 + c;
        float s[4];
#pragma unroll
        for (int r = 0; r < 4; ++r) {
            float sum = 0.f;
#pragma unroll
            for (int i = 0; i < 4; ++i) {
                const int col = cg*64 + i*16 + lane16;
                sum += tanhf(acc[c][i][r] + ba1[col]) * Wa2[col];
            }
            s[r] = sum;
        }
#pragma unroll
        for (int m = 1; m <= 8; m <<= 1)
#pragma unroll
            for (int r = 0; r < 4; ++r) s[r] += __shfl_xor(s[r], m);
        if (lane16 == 0) {
#pragma unroll
            for (int r = 0; r < 4; ++r)
                partials[(size_t)(rt*16 + qk*4 + r)*16 + cg] = s[r];
        }
    }
}

// ---------------------------------------------------------------------------
// 3) Softmax + h0/ctx + words seed (captions[:,0]).
// ---------------------------------------------------------------------------
__global__ void __launch_bounds__(256) k_attn_finish(
    const float* __restrict__ partials, const float* __restrict__ combined,
    const int* __restrict__ captions,
    float* __restrict__ A_out, float* __restrict__ h0,
    float* __restrict__ ctx, int* __restrict__ words)
{
    const int b = blockIdx.x, t = threadIdx.x;
    __shared__ float sc[NCOMB];
    __shared__ float red[256];

    for (int i = t; i < NCOMB; i += 256) {
        float s = 0.f;
        const float* pr = partials + (size_t)(b*NCOMB + i)*16;
#pragma unroll
        for (int g = 0; g < 16; ++g) s += pr[g];
        sc[i] = s;
    }
    __syncthreads();
    float m = -1e30f;
    for (int i = t; i < NCOMB; i += 256) m = fmaxf(m, sc[i]);
    red[t] = m; __syncthreads();
    for (int s2 = 128; s2 > 0; s2 >>= 1) {
        if (t < s2) red[t] = fmaxf(red[t], red[t+s2]);
        __syncthreads();
    }
    m = red[0]; __syncthreads();
    float ssum = 0.f;
    for (int i = t; i < NCOMB; i += 256) { float e = expf(sc[i] - m); sc[i] = e; ssum += e; }
    red[t] = ssum; __syncthreads();
    for (int s2 = 128; s2 > 0; s2 >>= 1) {
        if (t < s2) red[t] += red[t+s2];
        __syncthreads();
    }
    const float S = red[0]; __syncthreads();
    for (int i = t; i < NCOMB; i += 256) {
        const float a = sc[i] / S;
        sc[i] = a;
        A_out[b*NCOMB + i] = a;
    }
    __syncthreads();
    for (int e = t; e < HD; e += 256) {
        float acc = 0.f;
        const float* cb = combined + (size_t)b*NCOMB*ED + e;
        for (int i = 0; i < NCOMB; ++i) acc = fmaf(sc[i], cb[(size_t)i*ED], acc);
        h0[(size_t)b*HD + e] = acc;
        ctx[(size_t)b*HD + e] = acc;
    }
    if (t == 0) words[b] = captions[b*SEQL];
}

// ---------------------------------------------------------------------------
// 3b) gi_ctx (step-invariant).
// ---------------------------------------------------------------------------
__global__ void __launch_bounds__(256) k_gictx(
    const float* __restrict__ W_ih, const float* __restrict__ b_ih,
    const float* __restrict__ ctx, float* __restrict__ gictx)
{
    const int jj = blockIdx.x;           // 0..3071
    const int t = threadIdx.x;
    const int w = t >> 6, l = t & 63;
    const int b0 = w*8;
    const float* Wrow = W_ih + (size_t)jj*(ED+HD) + ED;

    float a[8];
#pragma unroll
    for (int i = 0; i < 8; ++i) a[i] = 0.f;
#pragma unroll
    for (int q = 0; q < 4; ++q) {
        const int k = q*256 + l*4;
        const float4 wv = *(const float4*)(Wrow + k);
#pragma unroll
        for (int i = 0; i < 8; ++i) {
            const float4 xv = *(const float4*)(ctx + (size_t)(b0 + i)*HD + k);
            DOT4(a[i], wv, xv);
        }
    }
    int s = (l >> 5) & 1;
    int ib = s*4;
    float tA[4];
#pragma unroll
    for (int ii = 0; ii < 4; ++ii) {
        const float send = a[(1^s)*4 + ii];
        tA[ii] = a[s*4 + ii] + __shfl_xor(send, 32);
    }
    s = (l >> 4) & 1; ib += s*2;
    float tB[2];
#pragma unroll
    for (int jj2 = 0; jj2 < 2; ++jj2) {
        const float send = tA[(1^s)*2 + jj2];
        tB[jj2] = tA[s*2 + jj2] + __shfl_xor(send, 16);
    }
    s = (l >> 3) & 1; ib += s;
    float fg;
    {
        const float send = tB[1^s];
        fg = tB[s] + __shfl_xor(send, 8);
    }
#pragma unroll
    for (int mm = 4; mm >= 1; mm >>= 1) fg += __shfl_xor(fg, mm);
    if ((l & 7) == 0)
        gictx[(size_t)jj*NB + (b0 + ib)] = fg + b_ih[jj];
}

// ---------------------------------------------------------------------------
// 3c) Standalone gh seed for step 1 (from h0).
// ---------------------------------------------------------------------------
__global__ void __launch_bounds__(256) k_gh(
    const float* __restrict__ W_hh, const float* __restrict__ h,
    float* __restrict__ gh)
{
    const int t = threadIdx.x;
    gh_body(blockIdx.x, W_hh, h, gh, t >> 6, t & 63);
}

// ---------------------------------------------------------------------------
// 4) GRU rest: emb part + gates via precomputed gh + gictx. Reads words[]
//    (exact argmax from k_rescore). Fused h frag pack.
// ---------------------------------------------------------------------------
__global__ void __launch_bounds__(256) k_gru_rest(
    const float* __restrict__ emb, const float* __restrict__ W_ih,
    const float* __restrict__ gh, const float* __restrict__ gictx,
    const float* __restrict__ b_hh,
    const float* __restrict__ h_prev, float* __restrict__ h_next,
    const int* __restrict__ words,
    uint* __restrict__ Hhi, uint* __restrict__ Hlo)
{
    __shared__ int word_s[NB];
    const int t = threadIdx.x;
    if (t < NB) word_s[t] = words[t];
    __syncthreads();

    const int j = blockIdx.x;
    const int w = t >> 6, l = t & 63;
    const int b0 = w*8;

    float a[3][8];
#pragma unroll
    for (int g = 0; g < 3; ++g)
#pragma unroll
        for (int i = 0; i < 8; ++i) a[g][i] = 0.f;

    const float* Wr = W_ih + (size_t)j*(ED+HD);
    const float* Wz = W_ih + (size_t)(HD + j)*(ED+HD);
    const float* Wn = W_ih + (size_t)(2*HD + j)*(ED+HD);
#pragma unroll
    for (int q = 0; q < 4; ++q) {
        const int k = q*256 + l*4;
        const float4 wr = *(const float4*)(Wr + k);
        const float4 wz = *(const float4*)(Wz + k);
        const float4 wn = *(const float4*)(Wn + k);
#pragma unroll
        for (int i = 0; i < 8; ++i) {
            const float4 xv = *(const float4*)(emb + (size_t)word_s[b0+i]*ED + k);
            DOT4(a[0][i], wr, xv);
            DOT4(a[1][i], wz, xv);
            DOT4(a[2][i], wn, xv);
        }
    }
    int s = (l >> 5) & 1;
    int ib = s*4;
    float tA[3][4];
#pragma unroll
    for (int g = 0; g < 3; ++g)
#pragma unroll
        for (int ii = 0; ii < 4; ++ii) {
            const float send = a[g][(1^s)*4 + ii];
            tA[g][ii] = a[g][s*4 + ii] + __shfl_xor(send, 32);
        }
    s = (l >> 4) & 1; ib += s*2;
    float tB[3][2];
#pragma unroll
    for (int g = 0; g < 3; ++g)
#pragma unroll
        for (int jj = 0; jj < 2; ++jj) {
            const float send = tA[g][(1^s)*2 + jj];
            tB[g][jj] = tA[g][s*2 + jj] + __shfl_xor(send, 16);
        }
    s = (l >> 3) & 1; ib += s;
    float fg[3];
#pragma unroll
    for (int g = 0; g < 3; ++g) {
        const float send = tB[g][1^s];
        fg[g] = tB[g][s] + __shfl_xor(send, 8);
    }
#pragma unroll
    for (int mm = 4; mm >= 1; mm >>= 1)
#pragma unroll
        for (int g = 0; g < 3; ++g) fg[g] += __shfl_xor(fg[g], mm);

    if ((l & 7) == 0) {
        const int b = b0 + ib;
        const float gcr = gictx[(size_t)j*NB + b];
        const float gcz = gictx[(size_t)(HD + j)*NB + b];
        const float gcn = gictx[(size_t)(2*HD + j)*NB + b];
        const float ghr = gh[(size_t)(0*HD + j)*NB + b];
        const float ghz = gh[(size_t)(1*HD + j)*NB + b];
        const float ghn = gh[(size_t)(2*HD + j)*NB + b];
        const float rg = 1.f/(1.f + expf(-(fg[0] + ghr + gcr + b_hh[j])));
        const float zg = 1.f/(1.f + expf(-(fg[1] + ghz + gcz + b_hh[HD+j])));
        const float ng = tanhf(fg[2] + gcn + rg*(ghn + b_hh[2*HD+j]));
        const float hp = h_prev[(size_t)b*HD + j];
        const float hv = (1.f - zg)*ng + zg*hp;
        h_next[(size_t)b*HD + j] = hv;
        __hip_bfloat16 hb = __float2bfloat16(hv);
        const float hf = __bfloat162float(hb);
        __hip_bfloat16 lb = __float2bfloat16(hv - hf);
        const int bh = b >> 4;
        const int ks = j >> 5;
        const int qk2 = (j >> 2) & 3;
        const int elem = (j & 3) + 4*((j >> 4) & 1);
        const size_t ei = (((size_t)(bh*32 + ks))*64 + qk2*16 + (b & 15))*8 + elem;
        ((ushort*)Hhi)[ei] = *(const ushort*)&hb;
        ((ushort*)Hlo)[ei] = *(const ushort*)&lb;
    }
}

// ---------------------------------------------------------------------------
// 5) Fused: 2-term logits (whi x (hhi+hlo); stored values within threshold,
//    no argmax machinery) + next-step gh blocks.
// ---------------------------------------------------------------------------
__global__ void __launch_bounds__(256) k_logits_gh(
    const float* __restrict__ W_fc, const uint* __restrict__ Wfchi,
    const uint* __restrict__ Hhi, const uint* __restrict__ Hlo,
    const float* __restrict__ b_fc, float* __restrict__ out, int tstep,
    int packed, const float* __restrict__ W_hh,
    const float* __restrict__ hcur, float* __restrict__ gh)
{
    __shared__ float sm[32][68];
    __shared__ float mergebuf[2][64][16];
    const int t = threadIdx.x;
    const int w = t >> 6, l = t & 63;

    if (blockIdx.x >= LBLK) {
        gh_body(blockIdx.x - LBLK, W_hh, hcur, gh, w, l);
        return;
    }

    const int lane16 = l & 15, qk = (l >> 4) & 3;
    const int tp = w & 1;                   // tile-pair within block
    const int kh = w >> 1;                  // K half
    const int tile0 = blockIdx.x*4 + tp*2;

    const u32x4* hh0 = (const u32x4*)Hhi + (size_t)(kh*16)*64 + l;
    const u32x4* hl0 = (const u32x4*)Hlo + (size_t)(kh*16)*64 + l;
    const u32x4* hh1 = (const u32x4*)Hhi + (size_t)(32 + kh*16)*64 + l;
    const u32x4* hl1 = (const u32x4*)Hlo + (size_t)(32 + kh*16)*64 + l;

    f32x4 accA0 = {0.f,0.f,0.f,0.f};
    f32x4 accA1 = {0.f,0.f,0.f,0.f};
    f32x4 accB0 = {0.f,0.f,0.f,0.f};
    f32x4 accB1 = {0.f,0.f,0.f,0.f};

    if (packed) {
        const u32x4* WHa = (const u32x4*)Wfchi + ((size_t)tile0*32 + kh*16)*64 + l;
        const u32x4* WHb = WHa + (size_t)32*64;
#pragma unroll 2
        for (int ks = 0; ks < 16; ++ks) {
            FragU wha, whb, b0h, b0l, b1h, b1l;
            wha.u = WHa[ks*64];
            whb.u = WHb[ks*64];
            b0h.u = hh0[ks*64];
            b0l.u = hl0[ks*64];
            b1h.u = hh1[ks*64];
            b1l.u = hl1[ks*64];
            accA0 = __builtin_amdgcn_mfma_f32_16x16x32_bf16(wha.s, b0h.s, accA0, 0, 0, 0);
            accA0 = __builtin_amdgcn_mfma_f32_16x16x32_bf16(wha.s, b0l.s, accA0, 0, 0, 0);
            accA1 = __builtin_amdgcn_mfma_f32_16x16x32_bf16(wha.s, b1h.s, accA1, 0, 0, 0);
            accA1 = __builtin_amdgcn_mfma_f32_16x16x32_bf16(wha.s, b1l.s, accA1, 0, 0, 0);
            accB0 = __builtin_amdgcn_mfma_f32_16x16x32_bf16(whb.s, b0h.s, accB0, 0, 0, 0);
            accB0 = __builtin_amdgcn_mfma_f32_16x16x32_bf16(whb.s, b0l.s, accB0, 0, 0, 0);
            accB1 = __builtin_amdgcn_mfma_f32_16x16x32_bf16(whb.s, b1h.s, accB1, 0, 0, 0);
            accB1 = __builtin_amdgcn_mfma_f32_16x16x32_bf16(whb.s, b1l.s, accB1, 0, 0, 0);
        }
    } else {
        const float* WrowA = W_fc + (size_t)(tile0*16 + lane16)*HD;
        const float* WrowB = W_fc + (size_t)((tile0 + 1)*16 + lane16)*HD;
#pragma unroll 2
        for (int ks = 0; ks < 16; ++ks) {
            const int k0 = (kh*16 + ks)*32 + qk*4;
            const float4 waA = *(const float4*)(WrowA + k0);
            const float4 wbA = *(const float4*)(WrowA + k0 + 16);
            const float4 waB = *(const float4*)(WrowB + k0);
            const float4 wbB = *(const float4*)(WrowB + k0 + 16);
            FragU wha, whb;
            wha.u = (u32x4){cvt2(waA.x, waA.y), cvt2(waA.z, waA.w),
                            cvt2(wbA.x, wbA.y), cvt2(wbA.z, wbA.w)};
            whb.u = (u32x4){cvt2(waB.x, waB.y), cvt2(waB.z, waB.w),
                            cvt2(wbB.x, wbB.y), cvt2(wbB.z, wbB.w)};
            FragU b0h, b0l, b1h, b1l;
            b0h.u = hh0[ks*64];
            b0l.u = hl0[ks*64];
            b1h.u = hh1[ks*64];
            b1l.u = hl1[ks*64];
            accA0 = __builtin_amdgcn_mfma_f32_16x16x32_bf16(wha.s, b0h.s, accA0, 0, 0, 0);
            accA0 = __builtin_amdgcn_mfma_f32_16x16x32_bf16(wha.s, b0l.s, accA0, 0, 0, 0);
            accA1 = __builtin_amdgcn_mfma_f32_16x16x32_bf16(wha.s, b1h.s, accA1, 0, 0, 0);
            accA1 = __builtin_amdgcn_mfma_f32_16x16x32_bf16(wha.s, b1l.s, accA1, 0, 0, 0);
            accB0 = __builtin_amdgcn_mfma_f32_16x16x32_bf16(whb.s, b0h.s, accB0, 0, 0, 0);
            accB0 = __builtin_amdgcn_mfma_f32_16x16x32_bf16(whb.s, b0l.s, accB0, 0, 0, 0);
            accB1 = __builtin_amdgcn_mfma_f32_16x16x32_bf16(whb.s, b1h.s, accB1, 0, 0, 0);
            accB1 = __builtin_amdgcn_mfma_f32_16x16x32_bf16(whb.s, b1l.s, accB1, 0, 0, 0);
        }
    }

    if (kh == 1) {
        float* rr = &mergebuf[tp][l][0];
        *(float4*)&rr[0]  = make_float4(accA0[0], accA0[1], accA0[2], accA0[3]);
        *(float4*)&rr[4]  = make_float4(accA1[0], accA1[1], accA1[2], accA1[3]);
        *(float4*)&rr[8]  = make_float4(accB0[0], accB0[1], accB0[2], accB0[3]);
        *(float4*)&rr[12] = make_float4(accB1[0], accB1[1], accB1[2], accB1[3]);
    }
    __syncthreads();
    if (kh == 0) {
        const float* rr = &mergebuf[tp][l][0];
        const float4 biasA = *(const float4*)&b_fc[tile0*16 + qk*4];
        const float4 biasB = *(const float4*)&b_fc[(tile0 + 1)*16 + qk*4];
#pragma unroll
        for (int r = 0; r < 4; ++r) {
            const int rlocA = tp*32 + qk*4 + r;
            const int rlocB = tp*32 + 16 + qk*4 + r;
            const float bA = (&biasA.x)[r];
            const float bB = (&biasB.x)[r];
            sm[lane16][rlocA]      = accA0[r] + rr[r]      + bA;
            sm[16 + lane16][rlocA] = accA1[r] + rr[4 + r]  + bA;
            sm[lane16][rlocB]      = accB0[r] + rr[8 + r]  + bB;
            sm[16 + lane16][rlocB] = accB1[r] + rr[12 + r] + bB;
        }
    }
    __syncthreads();
    {
        const int b = t >> 3;
        const int rl0 = (t & 7)*8;
        const int vbase = blockIdx.x*64 + rl0;
        float* dst = out + (size_t)b*((size_t)SEQL*VOC) + (size_t)tstep*VOC + vbase;
        nt_store4(dst,     sm[b][rl0+0], sm[b][rl0+1], sm[b][rl0+2], sm[b][rl0+3]);
        nt_store4(dst + 4, sm[b][rl0+4], sm[b][rl0+5], sm[b][rl0+6], sm[b][rl0+7]);
    }
}

// ---------------------------------------------------------------------------
// 6) Exact argmax via rescore: per batch, scan stored (2-term) logits for
//    max and candidates within RESC_MARGIN (provably contains the exact
//    argmax since margin > 2x max 2-term error), rescore candidates exactly
//    in f32, first-index tie-break -> words[b].
// ---------------------------------------------------------------------------
__global__ void __launch_bounds__(256) k_rescore(
    const float* __restrict__ out, const float* __restrict__ W_fc,
    const float* __restrict__ b_fc, const float* __restrict__ h,
    int* __restrict__ words, int tstep)
{
    const int b = blockIdx.x, t = threadIdx.x;
    const float* row = out + (size_t)b*((size_t)SEQL*VOC) + (size_t)tstep*VOC;
    __shared__ float red[256];
    __shared__ int cand[MAXCAND];
    __shared__ int ncand_s;
    __shared__ ull wkey[4];

    // pass A: block max of stored logits
    float m = -1e30f;
    for (int i = t*4; i < VOC; i += 1024) {
        const float4 v = *(const float4*)&row[i];
        m = fmaxf(m, fmaxf(fmaxf(v.x, v.y), fmaxf(v.z, v.w)));
    }
    red[t] = m; __syncthreads();
    for (int s = 128; s > 0; s >>= 1) {
        if (t < s) red[t] = fmaxf(red[t], red[t+s]);
        __syncthreads();
    }
    const float thresh = red[0] - RESC_MARGIN;
    if (t == 0) ncand_s = 0;
    __syncthreads();

    // pass B: collect candidate indices (typically 1)
    for (int i = t*4; i < VOC; i += 1024) {
        const float4 v = *(const float4*)&row[i];
#pragma unroll
        for (int e = 0; e < 4; ++e) {
            if ((&v.x)[e] >= thresh) {
                int slot = atomicAdd(&ncand_s, 1);
                if (slot < MAXCAND) cand[slot] = i + e;
            }
        }
    }
    __syncthreads();
    const int nc = (ncand_s < MAXCAND) ? ncand_s : MAXCAND;

    // pass C: exact f32 rescore; wave w handles candidates w, w+4, ...
    const int w = t >> 6, l = t & 63;
    ull bk = 0ull;
    for (int c = w; c < nc; c += 4) {
        const int rg = cand[c];
        const float* wr = W_fc + (size_t)rg*HD;
        const float* hb = h + (size_t)b*HD;
        float acc = 0.f;
#pragma unroll
        for (int q = 0; q < 4; ++q) {
            const int k = q*256 + l*4;
            const float4 wv = *(const float4*)(wr + k);
            const float4 hv = *(const float4*)(hb + k);
            DOT4(acc, wv, hv);
        }
#pragma unroll
        for (int mm = 32; mm >= 1; mm >>= 1) acc += __shfl_xor(acc, mm);
        const float score = acc + b_fc[rg];
        const ull key = (((ull)enc_f32(score)) << 32) | (ull)(~(uint)rg);
        bk = (key > bk) ? key : bk;
    }
    if (l == 0) wkey[w] = bk;
    __syncthreads();
    if (t == 0) {
        ull best = wkey[0];
#pragma unroll
        for (int i = 1; i < 4; ++i) best = (wkey[i] > best) ? wkey[i] : best;
        words[b] = (int)(~(uint)best);
    }
}

// ---------------------------------------------------------------------------
extern "C" void kernel_launch(void* const* d_in, const int* in_sizes, int n_in,
                              void* d_out, int out_size, void* d_ws, size_t ws_size,
                              hipStream_t stream)
{
    const float* features = (const float*)d_in[0];
    const int*   captions = (const int*)d_in[1];
    const float* emb  = (const float*)d_in[3];
    const float* Wa1  = (const float*)d_in[4];
    const float* ba1  = (const float*)d_in[5];
    const float* Wa2  = (const float*)d_in[6];
    const float* W_ih = (const float*)d_in[8];
    const float* W_hh = (const float*)d_in[9];
    const float* b_ih = (const float*)d_in[10];
    const float* b_hh = (const float*)d_in[11];
    const float* W_fc = (const float*)d_in[12];
    const float* b_fc = (const float*)d_in[13];

    float* out = (float*)d_out;
    float* A_out = out + (size_t)NB*SEQL*VOC;

    char* wsp = (char*)d_ws;
    float* combined = (float*)wsp;  wsp += (size_t)NROWS*ED*4;     // 34 MB
    float* partials = (float*)wsp;  wsp += (size_t)NROWS*16*4;
    float* hbuf0    = (float*)wsp;  wsp += (size_t)NB*HD*4;
    float* hbuf1    = (float*)wsp;  wsp += (size_t)NB*HD*4;
    float* ctx      = (float*)wsp;  wsp += (size_t)NB*HD*4;
    int*   words    = (int*)wsp;    wsp += 256;                    // [32] padded
    uint*  Hhi      = (uint*)wsp;   wsp += (size_t)4096*16;        // 64 KB
    uint*  Hlo      = (uint*)wsp;   wsp += (size_t)4096*16;        // 64 KB
    uint*  W1hi     = (uint*)wsp;   wsp += (size_t)131072*16;      // 2 MB
    uint*  W1lo     = (uint*)wsp;   wsp += (size_t)131072*16;      // 2 MB
    float* gictx    = (float*)wsp;  wsp += (size_t)3*HD*NB*4;      // 393 KB
    float* gh       = (float*)wsp;  wsp += (size_t)3*HD*NB*4;      // 393 KB
    uint*  Wfchi    = (uint*)wsp;   wsp += (size_t)NTILE*32*64*16; // 62.5 MB
    size_t packed_need = (size_t)(wsp - (char*)d_ws);
    const int packed = (ws_size >= packed_need) ? 1 : 0;

    k_build<<<NROWS + 1000, 256, 0, stream>>>(features, captions, emb, combined, out);
    k_pack_w1<<<512, 256, 0, stream>>>(Wa1, W1hi, W1lo);
    if (packed)
        k_pack_wfc<<<NTILE*32*64/256, 256, 0, stream>>>(W_fc, Wfchi);
    k_attn_mfma<<<dim3(130, 8), 256, 0, stream>>>(combined, W1hi, W1lo, ba1, Wa2, partials);
    k_attn_finish<<<NB, 256, 0, stream>>>(partials, combined, captions,
                                          A_out, hbuf0, ctx, words);
    k_gictx<<<3*HD, 256, 0, stream>>>(W_ih, b_ih, ctx, gictx);
    k_gh<<<HD, 256, 0, stream>>>(W_hh, hbuf0, gh);   // gh for step 1 from h0
    for (int t = 1; t < SEQL; ++t) {
        const float* hp = (t & 1) ? hbuf0 : hbuf1;
        float*       hn = (t & 1) ? hbuf1 : hbuf0;
        k_gru_rest<<<HD, 256, 0, stream>>>(emb, W_ih, gh, gictx, b_hh,
                                           hp, hn, words, Hhi, Hlo);
        k_logits_gh<<<LBLK + HD, 256, 0, stream>>>(W_fc, Wfchi, Hhi, Hlo,
                                                   b_fc, out, t, packed,
                                                   W_hh, hn, gh);
        if (t < SEQL - 1)
            k_rescore<<<NB, 256, 0, stream>>>(out, W_fc, b_fc, hn, words, t);
    }
}

// Round 17
// 3651.463 us; speedup vs baseline: 1.1857x; 1.1857x over previous
//
#include <hip/hip_runtime.h>
#include <hip/hip_bf16.h>

typedef unsigned long long ull;
typedef unsigned int uint;

#define NB 32
#define NFEAT 196
#define SEQL 64
#define ED 1024
#define HD 1024
#define VOC 32000
#define NCOMB 260                  // NFEAT + SEQL
#define NROWS (NB*NCOMB)           // 8320
#define NTILE 2000                 // 16-row vocab tiles
#define LBLK (NTILE/4)             // 500 logits blocks (R13 config)

typedef __attribute__((ext_vector_type(8))) short s16x8;   // 8 bf16 = 4 VGPRs
typedef __attribute__((ext_vector_type(4))) float f32x4;
typedef __attribute__((ext_vector_type(4))) uint  u32x4;

union FragU { u32x4 u; s16x8 s; };

#define DOT4(acc, wv, xv) acc = fmaf((wv).x,(xv).x, fmaf((wv).y,(xv).y, fmaf((wv).z,(xv).z, fmaf((wv).w,(xv).w,(acc)))))

__device__ __forceinline__ uint enc_f32(float f) {
    uint u = __float_as_uint(f);
    return (u & 0x80000000u) ? ~u : (u | 0x80000000u);
}
__device__ __forceinline__ ull shflxor64(ull v, int m) {
    uint lo = __shfl_xor((uint)v, m);
    uint hi = __shfl_xor((uint)(v >> 32), m);
    return (((ull)hi) << 32) | (ull)lo;
}

// full split (hi + residual lo). 3-term products are REQUIRED: R10 proved the
// dropped wlo*h term (~2e-4 std, ~1e-3 max) flips argmax decisions.
__device__ __forceinline__ void split2(float a, float b, uint& hi, uint& lo) {
    __hip_bfloat162 h2 = __float22bfloat162_rn(make_float2(a, b));
    float2 hf = __bfloat1622float2(h2);
    __hip_bfloat162 l2 = __float22bfloat162_rn(make_float2(a - hf.x, b - hf.y));
    hi = *(uint*)&h2;
    lo = *(uint*)&l2;
}

// nontemporal float4 store: keep `out` stream from evicting L3-resident weights
__device__ __forceinline__ void nt_store4(float* p, float a, float b, float c, float d) {
    f32x4 v = {a, b, c, d};
    __builtin_nontemporal_store(v, (f32x4*)p);
}

// ---------------------------------------------------------------------------
// gh body: gh[g][j][b] = (W_hh rows {j, H+j, 2H+j}) . h[b]   (no biases).
// Same wave layout / butterfly order as the proven k_gru W_hh half.
// ---------------------------------------------------------------------------
__device__ __forceinline__ void gh_body(
    int j, const float* __restrict__ W_hh, const float* __restrict__ h,
    float* __restrict__ gh, int w, int l)
{
    const int b0 = w*8;
    float a[3][8];
#pragma unroll
    for (int g = 0; g < 3; ++g)
#pragma unroll
        for (int i = 0; i < 8; ++i) a[g][i] = 0.f;

    const float* Ur = W_hh + (size_t)j*HD;
    const float* Uz = W_hh + (size_t)(HD + j)*HD;
    const float* Un = W_hh + (size_t)(2*HD + j)*HD;
#pragma unroll
    for (int q = 0; q < 4; ++q) {
        const int k = q*256 + l*4;
        const float4 ur = *(const float4*)(Ur + k);
        const float4 uz = *(const float4*)(Uz + k);
        const float4 un = *(const float4*)(Un + k);
#pragma unroll
        for (int i = 0; i < 8; ++i) {
            const float4 hv = *(const float4*)(h + (size_t)(b0+i)*HD + k);
            DOT4(a[0][i], ur, hv);
            DOT4(a[1][i], uz, hv);
            DOT4(a[2][i], un, hv);
        }
    }
    int s = (l >> 5) & 1;
    int ib = s*4;
    float tA[3][4];
#pragma unroll
    for (int g = 0; g < 3; ++g)
#pragma unroll
        for (int ii = 0; ii < 4; ++ii) {
            const float send = a[g][(1^s)*4 + ii];
            tA[g][ii] = a[g][s*4 + ii] + __shfl_xor(send, 32);
        }
    s = (l >> 4) & 1; ib += s*2;
    float tB[3][2];
#pragma unroll
    for (int g = 0; g < 3; ++g)
#pragma unroll
        for (int jj = 0; jj < 2; ++jj) {
            const float send = tA[g][(1^s)*2 + jj];
            tB[g][jj] = tA[g][s*2 + jj] + __shfl_xor(send, 16);
        }
    s = (l >> 3) & 1; ib += s;
    float fg[3];
#pragma unroll
    for (int g = 0; g < 3; ++g) {
        const float send = tB[g][1^s];
        fg[g] = tB[g][s] + __shfl_xor(send, 8);
    }
#pragma unroll
    for (int mm = 4; mm >= 1; mm >>= 1)
#pragma unroll
        for (int g = 0; g < 3; ++g) fg[g] += __shfl_xor(fg[g], mm);

    if ((l & 7) == 0) {
        const int b = b0 + ib;
        gh[(size_t)(0*HD + j)*NB + b] = fg[0];
        gh[(size_t)(1*HD + j)*NB + b] = fg[1];
        gh[(size_t)(2*HD + j)*NB + b] = fg[2];
    }
}

// ---------------------------------------------------------------------------
// 1) Build combined = [features ; emb[captions]]; zero outputs[:,0,:] (nt).
// ---------------------------------------------------------------------------
__global__ void __launch_bounds__(256) k_build(
    const float* __restrict__ features, const int* __restrict__ captions,
    const float* __restrict__ emb, float* __restrict__ combined,
    float* __restrict__ out)
{
    const int bid = blockIdx.x;
    const int t = threadIdx.x;
    if (bid < NROWS) {
        const int b = bid / NCOMB;
        const int i = bid - b*NCOMB;
        const float* src = (i < NFEAT)
            ? (features + ((size_t)(b*NFEAT + i))*ED)
            : (emb + (size_t)captions[b*SEQL + (i - NFEAT)]*ED);
        float4* dst4 = (float4*)(combined + (size_t)bid*ED);
        const float4* s4 = (const float4*)src;
        dst4[t] = s4[t];
    } else {
        const int z = bid - NROWS;           // 0..999
        const int m = z*1024 + t*4;
        if (m < NB*VOC) {
            const int b = m / VOC;
            const int v = m - b*VOC;
            nt_store4(out + (size_t)b*((size_t)SEQL*VOC) + v, 0.f, 0.f, 0.f, 0.f);
        }
    }
}

// ---------------------------------------------------------------------------
// 1b) Pack Wa1 into hi/lo bf16 B-fragments.
// ---------------------------------------------------------------------------
__global__ void __launch_bounds__(256) k_pack_w1(
    const float* __restrict__ Wa1, uint* __restrict__ W1hi, uint* __restrict__ W1lo)
{
    const int eid = blockIdx.x*256 + threadIdx.x;      // 0..131071
    const int lane = eid & 63;
    const int ks = (eid >> 6) & 31;
    const int ct = eid >> 11;                          // 0..63
    const int c = ct*16 + (lane & 15);
    const int k0 = ks*32 + ((lane >> 4) & 3)*4;
    const float4 wa = *(const float4*)&Wa1[(size_t)c*ED + k0];
    const float4 wb = *(const float4*)&Wa1[(size_t)c*ED + k0 + 16];
    uint hi[4], lo[4];
    split2(wa.x, wa.y, hi[0], lo[0]);
    split2(wa.z, wa.w, hi[1], lo[1]);
    split2(wb.x, wb.y, hi[2], lo[2]);
    split2(wb.z, wb.w, hi[3], lo[3]);
    *(u32x4*)&W1hi[(size_t)eid*4] = (u32x4){hi[0], hi[1], hi[2], hi[3]};
    *(u32x4*)&W1lo[(size_t)eid*4] = (u32x4){lo[0], lo[1], lo[2], lo[3]};
}

// ---------------------------------------------------------------------------
// 1c) Pack W_fc into hi/lo bf16 A-fragments (3-term logits).
// ---------------------------------------------------------------------------
__global__ void __launch_bounds__(256) k_pack_wfc(
    const float* __restrict__ W_fc, uint* __restrict__ Whi, uint* __restrict__ Wlo)
{
    const int eid = blockIdx.x*256 + threadIdx.x;
    const int lane = eid & 63;
    const int ks = (eid >> 6) & 31;
    const int tile = eid >> 11;                        // 0..1999
    const int row = tile*16 + (lane & 15);
    const int k0 = ks*32 + ((lane >> 4) & 3)*4;
    const float4 wa = *(const float4*)&W_fc[(size_t)row*HD + k0];
    const float4 wb = *(const float4*)&W_fc[(size_t)row*HD + k0 + 16];
    uint hi[4], lo[4];
    split2(wa.x, wa.y, hi[0], lo[0]);
    split2(wa.z, wa.w, hi[1], lo[1]);
    split2(wb.x, wb.y, hi[2], lo[2]);
    split2(wb.z, wb.w, hi[3], lo[3]);
    *(u32x4*)&Whi[(size_t)eid*4] = (u32x4){hi[0], hi[1], hi[2], hi[3]};
    *(u32x4*)&Wlo[(size_t)eid*4] = (u32x4){lo[0], lo[1], lo[2], lo[3]};
}

// ---------------------------------------------------------------------------
// 2) Attention GEMM via MFMA hi/lo 3-term, 2 col-groups per block (R13 exact).
// ---------------------------------------------------------------------------
__global__ void __launch_bounds__(256) k_attn_mfma(
    const float* __restrict__ combined, const uint* __restrict__ W1hi,
    const uint* __restrict__ W1lo, const float* __restrict__ ba1,
    const float* __restrict__ Wa2, float* __restrict__ partials)
{
    const int t = threadIdx.x;
    const int w = t >> 6, l = t & 63;
    const int lane16 = l & 15, qk = (l >> 4) & 3;
    const int rt = blockIdx.x*4 + w;
    const int cg0 = blockIdx.y*2;

    const float* Arow = combined + (size_t)(rt*16 + lane16)*ED;
    const u32x4* bh_base = (const u32x4*)W1hi + l;
    const u32x4* bl_base = (const u32x4*)W1lo + l;

    f32x4 acc[2][4];
#pragma unroll
    for (int c = 0; c < 2; ++c)
#pragma unroll
        for (int i = 0; i < 4; ++i) acc[c][i] = (f32x4){0.f,0.f,0.f,0.f};

#pragma unroll 2
    for (int ks = 0; ks < 32; ++ks) {
        const int k0 = ks*32 + qk*4;
        const float4 aa = *(const float4*)(Arow + k0);
        const float4 ab = *(const float4*)(Arow + k0 + 16);
        FragU ahi, alo;
        uint h0,l0_,h1,l1_,h2,l2_,h3,l3_;
        split2(aa.x, aa.y, h0, l0_);
        split2(aa.z, aa.w, h1, l1_);
        split2(ab.x, ab.y, h2, l2_);
        split2(ab.z, ab.w, h3, l3_);
        ahi.u = (u32x4){h0, h1, h2, h3};
        alo.u = (u32x4){l0_, l1_, l2_, l3_};
#pragma unroll
        for (int c = 0; c < 2; ++c) {
#pragma unroll
            for (int i = 0; i < 4; ++i) {
                const size_t idx = (((size_t)((cg0 + c)*4 + i))*32 + ks)*64;
                FragU bh_, bl_;
                bh_.u = bh_base[idx];
                bl_.u = bl_base[idx];
                acc[c][i] = __builtin_amdgcn_mfma_f32_16x16x32_bf16(ahi.s, bh_.s, acc[c][i], 0, 0, 0);
                acc[c][i] = __builtin_amdgcn_mfma_f32_16x16x32_bf16(ahi.s, bl_.s, acc[c][i], 0, 0, 0);
                acc[c][i] = __builtin_amdgcn_mfma_f32_16x16x32_bf16(alo.s, bh_.s, acc[c][i], 0, 0, 0);
            }
        }
    }

#pragma unroll
    for (int c = 0; c < 2; ++c) {
        const int cg = cg0 + c;
        float s[4];
#pragma unroll
        for (int r = 0; r < 4; ++r) {
            float sum = 0.f;
#pragma unroll
            for (int i = 0; i < 4; ++i) {
                const int col = cg*64 + i*16 + lane16;
                sum += tanhf(acc[c][i][r] + ba1[col]) * Wa2[col];
            }
            s[r] = sum;
        }
#pragma unroll
        for (int m = 1; m <= 8; m <<= 1)
#pragma unroll
            for (int r = 0; r < 4; ++r) s[r] += __shfl_xor(s[r], m);
        if (lane16 == 0) {
#pragma unroll
            for (int r = 0; r < 4; ++r)
                partials[(size_t)(rt*16 + qk*4 + r)*16 + cg] = s[r];
        }
    }
}

// ---------------------------------------------------------------------------
// 3) Softmax + h0/ctx + slot init (unchanged)
// ---------------------------------------------------------------------------
__global__ void __launch_bounds__(256) k_attn_finish(
    const float* __restrict__ partials, const float* __restrict__ combined,
    const int* __restrict__ captions,
    float* __restrict__ A_out, float* __restrict__ h0,
    float* __restrict__ ctx, ull* __restrict__ slots0)
{
    const int b = blockIdx.x, t = threadIdx.x;
    __shared__ float sc[NCOMB];
    __shared__ float red[256];

    for (int i = t; i < NCOMB; i += 256) {
        float s = 0.f;
        const float* pr = partials + (size_t)(b*NCOMB + i)*16;
#pragma unroll
        for (int g = 0; g < 16; ++g) s += pr[g];
        sc[i] = s;
    }
    __syncthreads();
    float m = -1e30f;
    for (int i = t; i < NCOMB; i += 256) m = fmaxf(m, sc[i]);
    red[t] = m; __syncthreads();
    for (int s2 = 128; s2 > 0; s2 >>= 1) {
        if (t < s2) red[t] = fmaxf(red[t], red[t+s2]);
        __syncthreads();
    }
    m = red[0]; __syncthreads();
    float ssum = 0.f;
    for (int i = t; i < NCOMB; i += 256) { float e = expf(sc[i] - m); sc[i] = e; ssum += e; }
    red[t] = ssum; __syncthreads();
    for (int s2 = 128; s2 > 0; s2 >>= 1) {
        if (t < s2) red[t] += red[t+s2];
        __syncthreads();
    }
    const float S = red[0]; __syncthreads();
    for (int i = t; i < NCOMB; i += 256) {
        const float a = sc[i] / S;
        sc[i] = a;
        A_out[b*NCOMB + i] = a;
    }
    __syncthreads();
    for (int e = t; e < HD; e += 256) {
        float acc = 0.f;
        const float* cb = combined + (size_t)b*NCOMB*ED + e;
        for (int i = 0; i < NCOMB; ++i) acc = fmaf(sc[i], cb[(size_t)i*ED], acc);
        h0[(size_t)b*HD + e] = acc;
        ctx[(size_t)b*HD + e] = acc;
    }
    if (t == 0) {
        slots0[0*NB + b] = (ull)(~(uint)captions[b*SEQL]);
#pragma unroll
        for (int g = 1; g < 8; ++g) slots0[g*NB + b] = 0ull;
    }
}

// ---------------------------------------------------------------------------
// 3b) gi_ctx[jj][b] = W_ih[jj, E:]*ctx[b] + b_ih[jj]  (step-invariant).
// ---------------------------------------------------------------------------
__global__ void __launch_bounds__(256) k_gictx(
    const float* __restrict__ W_ih, const float* __restrict__ b_ih,
    const float* __restrict__ ctx, float* __restrict__ gictx)
{
    const int jj = blockIdx.x;           // 0..3071
    const int t = threadIdx.x;
    const int w = t >> 6, l = t & 63;
    const int b0 = w*8;
    const float* Wrow = W_ih + (size_t)jj*(ED+HD) + ED;

    float a[8];
#pragma unroll
    for (int i = 0; i < 8; ++i) a[i] = 0.f;
#pragma unroll
    for (int q = 0; q < 4; ++q) {
        const int k = q*256 + l*4;
        const float4 wv = *(const float4*)(Wrow + k);
#pragma unroll
        for (int i = 0; i < 8; ++i) {
            const float4 xv = *(const float4*)(ctx + (size_t)(b0 + i)*HD + k);
            DOT4(a[i], wv, xv);
        }
    }
    int s = (l >> 5) & 1;
    int ib = s*4;
    float tA[4];
#pragma unroll
    for (int ii = 0; ii < 4; ++ii) {
        const float send = a[(1^s)*4 + ii];
        tA[ii] = a[s*4 + ii] + __shfl_xor(send, 32);
    }
    s = (l >> 4) & 1; ib += s*2;
    float tB[2];
#pragma unroll
    for (int jj2 = 0; jj2 < 2; ++jj2) {
        const float send = tA[(1^s)*2 + jj2];
        tB[jj2] = tA[s*2 + jj2] + __shfl_xor(send, 16);
    }
    s = (l >> 3) & 1; ib += s;
    float fg;
    {
        const float send = tB[1^s];
        fg = tB[s] + __shfl_xor(send, 8);
    }
#pragma unroll
    for (int mm = 4; mm >= 1; mm >>= 1) fg += __shfl_xor(fg, mm);
    if ((l & 7) == 0)
        gictx[(size_t)jj*NB + (b0 + ib)] = fg + b_ih[jj];
}

// ---------------------------------------------------------------------------
// 3c) Standalone gh seed for step 1 (from h0).
// ---------------------------------------------------------------------------
__global__ void __launch_bounds__(256) k_gh(
    const float* __restrict__ W_hh, const float* __restrict__ h,
    float* __restrict__ gh)
{
    const int t = threadIdx.x;
    gh_body(blockIdx.x, W_hh, h, gh, t >> 6, t & 63);
}

// ---------------------------------------------------------------------------
// 4) GRU rest: emb part + gates, combining precomputed gh (W_hh.h) and
//    gictx (W_ih.ctx + b_ih). Fused h frag pack.
// ---------------------------------------------------------------------------
__global__ void __launch_bounds__(256) k_gru_rest(
    const float* __restrict__ emb, const float* __restrict__ W_ih,
    const float* __restrict__ gh, const float* __restrict__ gictx,
    const float* __restrict__ b_hh,
    const float* __restrict__ h_prev, float* __restrict__ h_next,
    const ull* __restrict__ slots_prev, ull* __restrict__ slots_cur,
    uint* __restrict__ Hhi, uint* __restrict__ Hlo)
{
    __shared__ int word_s[NB];
    const int t = threadIdx.x;
    if (t < NB) {
        ull best = 0ull;
#pragma unroll
        for (int g = 0; g < 8; ++g) {
            ull k = slots_prev[g*NB + t];
            best = (k > best) ? k : best;
        }
        word_s[t] = (int)(~(uint)best);
    }
    if (blockIdx.x == 0) slots_cur[t] = 0ull;
    __syncthreads();

    const int j = blockIdx.x;
    const int w = t >> 6, l = t & 63;
    const int b0 = w*8;

    float a[3][8];
#pragma unroll
    for (int g = 0; g < 3; ++g)
#pragma unroll
        for (int i = 0; i < 8; ++i) a[g][i] = 0.f;

    const float* Wr = W_ih + (size_t)j*(ED+HD);
    const float* Wz = W_ih + (size_t)(HD + j)*(ED+HD);
    const float* Wn = W_ih + (size_t)(2*HD + j)*(ED+HD);
#pragma unroll
    for (int q = 0; q < 4; ++q) {
        const int k = q*256 + l*4;
        const float4 wr = *(const float4*)(Wr + k);
        const float4 wz = *(const float4*)(Wz + k);
        const float4 wn = *(const float4*)(Wn + k);
#pragma unroll
        for (int i = 0; i < 8; ++i) {
            const float4 xv = *(const float4*)(emb + (size_t)word_s[b0+i]*ED + k);
            DOT4(a[0][i], wr, xv);
            DOT4(a[1][i], wz, xv);
            DOT4(a[2][i], wn, xv);
        }
    }
    int s = (l >> 5) & 1;
    int ib = s*4;
    float tA[3][4];
#pragma unroll
    for (int g = 0; g < 3; ++g)
#pragma unroll
        for (int ii = 0; ii < 4; ++ii) {
            const float send = a[g][(1^s)*4 + ii];
            tA[g][ii] = a[g][s*4 + ii] + __shfl_xor(send, 32);
        }
    s = (l >> 4) & 1; ib += s*2;
    float tB[3][2];
#pragma unroll
    for (int g = 0; g < 3; ++g)
#pragma unroll
        for (int jj = 0; jj < 2; ++jj) {
            const float send = tA[g][(1^s)*2 + jj];
            tB[g][jj] = tA[g][s*2 + jj] + __shfl_xor(send, 16);
        }
    s = (l >> 3) & 1; ib += s;
    float fg[3];
#pragma unroll
    for (int g = 0; g < 3; ++g) {
        const float send = tB[g][1^s];
        fg[g] = tB[g][s] + __shfl_xor(send, 8);
    }
#pragma unroll
    for (int mm = 4; mm >= 1; mm >>= 1)
#pragma unroll
        for (int g = 0; g < 3; ++g) fg[g] += __shfl_xor(fg[g], mm);

    if ((l & 7) == 0) {
        const int b = b0 + ib;
        const float gcr = gictx[(size_t)j*NB + b];
        const float gcz = gictx[(size_t)(HD + j)*NB + b];
        const float gcn = gictx[(size_t)(2*HD + j)*NB + b];
        const float ghr = gh[(size_t)(0*HD + j)*NB + b];
        const float ghz = gh[(size_t)(1*HD + j)*NB + b];
        const float ghn = gh[(size_t)(2*HD + j)*NB + b];
        const float rg = 1.f/(1.f + expf(-(fg[0] + ghr + gcr + b_hh[j])));
        const float zg = 1.f/(1.f + expf(-(fg[1] + ghz + gcz + b_hh[HD+j])));
        const float ng = tanhf(fg[2] + gcn + rg*(ghn + b_hh[2*HD+j]));
        const float hp = h_prev[(size_t)b*HD + j];
        const float hv = (1.f - zg)*ng + zg*hp;
        h_next[(size_t)b*HD + j] = hv;
        __hip_bfloat16 hb = __float2bfloat16(hv);
        const float hf = __bfloat162float(hb);
        __hip_bfloat16 lb = __float2bfloat16(hv - hf);
        const int bh = b >> 4;
        const int ks = j >> 5;
        const int qk2 = (j >> 2) & 3;
        const int elem = (j & 3) + 4*((j >> 4) & 1);
        const size_t ei = (((size_t)(bh*32 + ks))*64 + qk2*16 + (b & 15))*8 + elem;
        ((ushort*)Hhi)[ei] = *(const ushort*)&hb;
        ((ushort*)Hlo)[ei] = *(const ushort*)&lb;
    }
}

// ---------------------------------------------------------------------------
// 5) Fused: logits (R13 2-tile x 2-K-split body, blocks < LBLK) + next-step
//    gh blocks (blocks >= LBLK; independent work, no sync).
// ---------------------------------------------------------------------------
__global__ void __launch_bounds__(256) k_logits_gh(
    const float* __restrict__ W_fc, const uint* __restrict__ Wfchi,
    const uint* __restrict__ Wfclo, const uint* __restrict__ Hhi,
    const uint* __restrict__ Hlo, const float* __restrict__ b_fc,
    float* __restrict__ out, ull* __restrict__ slots_cur, int tstep, int packed,
    const float* __restrict__ W_hh, const float* __restrict__ hcur,
    float* __restrict__ gh)
{
    __shared__ float sm[32][68];
    __shared__ float mergebuf[2][64][16];   // [tp][lane][A0 A1 B0 B1][r]
    const int t = threadIdx.x;
    const int w = t >> 6, l = t & 63;

    if (blockIdx.x >= LBLK) {
        gh_body(blockIdx.x - LBLK, W_hh, hcur, gh, w, l);
        return;
    }

    const int lane16 = l & 15, qk = (l >> 4) & 3;
    const int tp = w & 1;                   // tile-pair within block
    const int kh = w >> 1;                  // K half
    const int tile0 = blockIdx.x*4 + tp*2;  // first of this wave's 2 tiles

    const u32x4* hh0 = (const u32x4*)Hhi + (size_t)(kh*16)*64 + l;
    const u32x4* hl0 = (const u32x4*)Hlo + (size_t)(kh*16)*64 + l;
    const u32x4* hh1 = (const u32x4*)Hhi + (size_t)(32 + kh*16)*64 + l;
    const u32x4* hl1 = (const u32x4*)Hlo + (size_t)(32 + kh*16)*64 + l;

    f32x4 accA0 = {0.f,0.f,0.f,0.f};   // tile A, batches 0-15
    f32x4 accA1 = {0.f,0.f,0.f,0.f};   // tile A, batches 16-31
    f32x4 accB0 = {0.f,0.f,0.f,0.f};   // tile B, batches 0-15
    f32x4 accB1 = {0.f,0.f,0.f,0.f};   // tile B, batches 16-31

    if (packed) {
        const u32x4* WHa = (const u32x4*)Wfchi + ((size_t)tile0*32 + kh*16)*64 + l;
        const u32x4* WLa = (const u32x4*)Wfclo + ((size_t)tile0*32 + kh*16)*64 + l;
        const u32x4* WHb = WHa + (size_t)32*64;    // tile0+1
        const u32x4* WLb = WLa + (size_t)32*64;
#pragma unroll 2
        for (int ks = 0; ks < 16; ++ks) {
            FragU wha, wla, whb, wlb, b0h, b0l, b1h, b1l;
            wha.u = WHa[ks*64];
            wla.u = WLa[ks*64];
            whb.u = WHb[ks*64];
            wlb.u = WLb[ks*64];
            b0h.u = hh0[ks*64];
            b0l.u = hl0[ks*64];
            b1h.u = hh1[ks*64];
            b1l.u = hl1[ks*64];
            accA0 = __builtin_amdgcn_mfma_f32_16x16x32_bf16(wha.s, b0h.s, accA0, 0, 0, 0);
            accA0 = __builtin_amdgcn_mfma_f32_16x16x32_bf16(wha.s, b0l.s, accA0, 0, 0, 0);
            accA0 = __builtin_amdgcn_mfma_f32_16x16x32_bf16(wla.s, b0h.s, accA0, 0, 0, 0);
            accA1 = __builtin_amdgcn_mfma_f32_16x16x32_bf16(wha.s, b1h.s, accA1, 0, 0, 0);
            accA1 = __builtin_amdgcn_mfma_f32_16x16x32_bf16(wha.s, b1l.s, accA1, 0, 0, 0);
            accA1 = __builtin_amdgcn_mfma_f32_16x16x32_bf16(wla.s, b1h.s, accA1, 0, 0, 0);
            accB0 = __builtin_amdgcn_mfma_f32_16x16x32_bf16(whb.s, b0h.s, accB0, 0, 0, 0);
            accB0 = __builtin_amdgcn_mfma_f32_16x16x32_bf16(whb.s, b0l.s, accB0, 0, 0, 0);
            accB0 = __builtin_amdgcn_mfma_f32_16x16x32_bf16(wlb.s, b0h.s, accB0, 0, 0, 0);
            accB1 = __builtin_amdgcn_mfma_f32_16x16x32_bf16(whb.s, b1h.s, accB1, 0, 0, 0);
            accB1 = __builtin_amdgcn_mfma_f32_16x16x32_bf16(whb.s, b1l.s, accB1, 0, 0, 0);
            accB1 = __builtin_amdgcn_mfma_f32_16x16x32_bf16(wlb.s, b1h.s, accB1, 0, 0, 0);
        }
    } else {
        const float* WrowA = W_fc + (size_t)(tile0*16 + lane16)*HD;
        const float* WrowB = W_fc + (size_t)((tile0 + 1)*16 + lane16)*HD;
#pragma unroll 2
        for (int ks = 0; ks < 16; ++ks) {
            const int k0 = (kh*16 + ks)*32 + qk*4;
            const float4 waA = *(const float4*)(WrowA + k0);
            const float4 wbA = *(const float4*)(WrowA + k0 + 16);
            const float4 waB = *(const float4*)(WrowB + k0);
            const float4 wbB = *(const float4*)(WrowB + k0 + 16);
            FragU wha, wla, whb, wlb;
            uint h0,l0_,h1,l1_,h2,l2_,h3,l3_;
            split2(waA.x, waA.y, h0, l0_);
            split2(waA.z, waA.w, h1, l1_);
            split2(wbA.x, wbA.y, h2, l2_);
            split2(wbA.z, wbA.w, h3, l3_);
            wha.u = (u32x4){h0, h1, h2, h3};
            wla.u = (u32x4){l0_, l1_, l2_, l3_};
            split2(waB.x, waB.y, h0, l0_);
            split2(waB.z, waB.w, h1, l1_);
            split2(wbB.x, wbB.y, h2, l2_);
            split2(wbB.z, wbB.w, h3, l3_);
            whb.u = (u32x4){h0, h1, h2, h3};
            wlb.u = (u32x4){l0_, l1_, l2_, l3_};
            FragU b0h, b0l, b1h, b1l;
            b0h.u = hh0[ks*64];
            b0l.u = hl0[ks*64];
            b1h.u = hh1[ks*64];
            b1l.u = hl1[ks*64];
            accA0 = __builtin_amdgcn_mfma_f32_16x16x32_bf16(wha.s, b0h.s, accA0, 0, 0, 0);
            accA0 = __builtin_amdgcn_mfma_f32_16x16x32_bf16(wha.s, b0l.s, accA0, 0, 0, 0);
            accA0 = __builtin_amdgcn_mfma_f32_16x16x32_bf16(wla.s, b0h.s, accA0, 0, 0, 0);
            accA1 = __builtin_amdgcn_mfma_f32_16x16x32_bf16(wha.s, b1h.s, accA1, 0, 0, 0);
            accA1 = __builtin_amdgcn_mfma_f32_16x16x32_bf16(wha.s, b1l.s, accA1, 0, 0, 0);
            accA1 = __builtin_amdgcn_mfma_f32_16x16x32_bf16(wla.s, b1h.s, accA1, 0, 0, 0);
            accB0 = __builtin_amdgcn_mfma_f32_16x16x32_bf16(whb.s, b0h.s, accB0, 0, 0, 0);
            accB0 = __builtin_amdgcn_mfma_f32_16x16x32_bf16(whb.s, b0l.s, accB0, 0, 0, 0);
            accB0 = __builtin_amdgcn_mfma_f32_16x16x32_bf16(wlb.s, b0h.s, accB0, 0, 0, 0);
            accB1 = __builtin_amdgcn_mfma_f32_16x16x32_bf16(whb.s, b1h.s, accB1, 0, 0, 0);
            accB1 = __builtin_amdgcn_mfma_f32_16x16x32_bf16(whb.s, b1l.s, accB1, 0, 0, 0);
            accB1 = __builtin_amdgcn_mfma_f32_16x16x32_bf16(wlb.s, b1h.s, accB1, 0, 0, 0);
        }
    }

    // merge K halves: kh=1 writes partials to LDS, kh=0 adds + bias -> sm
    if (kh == 1) {
        float* rr = &mergebuf[tp][l][0];
        *(float4*)&rr[0]  = make_float4(accA0[0], accA0[1], accA0[2], accA0[3]);
        *(float4*)&rr[4]  = make_float4(accA1[0], accA1[1], accA1[2], accA1[3]);
        *(float4*)&rr[8]  = make_float4(accB0[0], accB0[1], accB0[2], accB0[3]);
        *(float4*)&rr[12] = make_float4(accB1[0], accB1[1], accB1[2], accB1[3]);
    }
    __syncthreads();
    if (kh == 0) {
        const float* rr = &mergebuf[tp][l][0];
        const float4 biasA = *(const float4*)&b_fc[tile0*16 + qk*4];
        const float4 biasB = *(const float4*)&b_fc[(tile0 + 1)*16 + qk*4];
#pragma unroll
        for (int r = 0; r < 4; ++r) {
            const int rlocA = tp*32 + qk*4 + r;        // tile A local row
            const int rlocB = tp*32 + 16 + qk*4 + r;   // tile B local row
            const float bA = (&biasA.x)[r];
            const float bB = (&biasB.x)[r];
            sm[lane16][rlocA]      = accA0[r] + rr[r]      + bA;
            sm[16 + lane16][rlocA] = accA1[r] + rr[4 + r]  + bA;
            sm[lane16][rlocB]      = accB0[r] + rr[8 + r]  + bB;
            sm[16 + lane16][rlocB] = accB1[r] + rr[12 + r] + bB;
        }
    }
    __syncthreads();
    {
        const int b = t >> 3;
        const int rl0 = (t & 7)*8;
        const int vbase = blockIdx.x*64 + rl0;
        float v[8];
        ull bk = 0ull;
#pragma unroll
        for (int e = 0; e < 8; ++e) {
            v[e] = sm[b][rl0 + e];
            const ull key = (((ull)enc_f32(v[e])) << 32) | (ull)(~(uint)(vbase + e));
            bk = (key > bk) ? key : bk;
        }
        float* dst = out + (size_t)b*((size_t)SEQL*VOC) + (size_t)tstep*VOC + vbase;
        nt_store4(dst,     v[0], v[1], v[2], v[3]);
        nt_store4(dst + 4, v[4], v[5], v[6], v[7]);
#pragma unroll
        for (int mm = 4; mm >= 1; mm >>= 1) {
            const ull o = shflxor64(bk, mm);
            bk = (o > bk) ? o : bk;
        }
        if ((t & 7) == 0) atomicMax(slots_cur + (blockIdx.x & 7)*NB + b, bk);
    }
}

// ---------------------------------------------------------------------------
extern "C" void kernel_launch(void* const* d_in, const int* in_sizes, int n_in,
                              void* d_out, int out_size, void* d_ws, size_t ws_size,
                              hipStream_t stream)
{
    const float* features = (const float*)d_in[0];
    const int*   captions = (const int*)d_in[1];
    const float* emb  = (const float*)d_in[3];
    const float* Wa1  = (const float*)d_in[4];
    const float* ba1  = (const float*)d_in[5];
    const float* Wa2  = (const float*)d_in[6];
    const float* W_ih = (const float*)d_in[8];
    const float* W_hh = (const float*)d_in[9];
    const float* b_ih = (const float*)d_in[10];
    const float* b_hh = (const float*)d_in[11];
    const float* W_fc = (const float*)d_in[12];
    const float* b_fc = (const float*)d_in[13];

    float* out = (float*)d_out;
    float* A_out = out + (size_t)NB*SEQL*VOC;

    char* wsp = (char*)d_ws;
    float* combined = (float*)wsp;  wsp += (size_t)NROWS*ED*4;     // 34 MB
    float* partials = (float*)wsp;  wsp += (size_t)NROWS*16*4;
    float* hbuf0    = (float*)wsp;  wsp += (size_t)NB*HD*4;
    float* hbuf1    = (float*)wsp;  wsp += (size_t)NB*HD*4;
    float* ctx      = (float*)wsp;  wsp += (size_t)NB*HD*4;
    ull*   slots    = (ull*)wsp;    wsp += 2*8*NB*sizeof(ull);     // [2][8][32]
    uint*  Hhi      = (uint*)wsp;   wsp += (size_t)4096*16;        // 64 KB
    uint*  Hlo      = (uint*)wsp;   wsp += (size_t)4096*16;        // 64 KB
    uint*  W1hi     = (uint*)wsp;   wsp += (size_t)131072*16;      // 2 MB
    uint*  W1lo     = (uint*)wsp;   wsp += (size_t)131072*16;      // 2 MB
    float* gictx    = (float*)wsp;  wsp += (size_t)3*HD*NB*4;      // 393 KB
    float* gh       = (float*)wsp;  wsp += (size_t)3*HD*NB*4;      // 393 KB
    uint*  Wfchi    = (uint*)wsp;   wsp += (size_t)NTILE*32*64*16; // 62.5 MB
    uint*  Wfclo    = (uint*)wsp;   wsp += (size_t)NTILE*32*64*16; // 62.5 MB
    size_t packed_need = (size_t)(wsp - (char*)d_ws);
    const int packed = (ws_size >= packed_need) ? 1 : 0;

    k_build<<<NROWS + 1000, 256, 0, stream>>>(features, captions, emb, combined, out);
    k_pack_w1<<<512, 256, 0, stream>>>(Wa1, W1hi, W1lo);
    if (packed)
        k_pack_wfc<<<NTILE*32*64/256, 256, 0, stream>>>(W_fc, Wfchi, Wfclo);
    k_attn_mfma<<<dim3(130, 8), 256, 0, stream>>>(combined, W1hi, W1lo, ba1, Wa2, partials);
    k_attn_finish<<<NB, 256, 0, stream>>>(partials, combined, captions,
                                          A_out, hbuf0, ctx, slots);
    k_gictx<<<3*HD, 256, 0, stream>>>(W_ih, b_ih, ctx, gictx);
    k_gh<<<HD, 256, 0, stream>>>(W_hh, hbuf0, gh);   // gh for step 1 from h0
    for (int t = 1; t < SEQL; ++t) {
        const float* hp = (t & 1) ? hbuf0 : hbuf1;
        float*       hn = (t & 1) ? hbuf1 : hbuf0;
        const ull* sp = slots + (size_t)((t - 1) & 1)*8*NB;
        ull*       scur = slots + (size_t)(t & 1)*8*NB;
        k_gru_rest<<<HD, 256, 0, stream>>>(emb, W_ih, gh, gictx, b_hh,
                                           hp, hn, sp, scur, Hhi, Hlo);
        k_logits_gh<<<LBLK + HD, 256, 0, stream>>>(W_fc, Wfchi, Wfclo, Hhi, Hlo,
                                                   b_fc, out, scur, t, packed,
                                                   W_hh, hn, gh);
    }
}